// Round 1
// 610.746 us; speedup vs baseline: 1.0883x; 1.0883x over previous
//
#include <hip/hip_runtime.h>
#include <cstdint>
#include <cstddef>

#define T_TOK 4096
#define HD 2048
#define ID 1408
#define NE 8
#define NA (T_TOK * 2)        // 8192 assignments (K=2)
#define MAXR 9216             // 8192 + 8*128 padding headroom
#define MAXT 80               // max row-tiles (<= 71 actually)
#define EIH ((size_t)NE * ID * HD)
#define N4 ((int)(EIH / 4))   // float4 count per weight tensor = 5,767,168
#define NCGU 2048             // cast blocks for gate+up (merged with gather)
#define NCASTD 1024           // cast blocks for down (merged with gateup)
#define NTILE_M (MAXR / 128)  // 72
#define NGEMM_GU (NTILE_M * (ID / 128))  // 792 (divisible by 8 -> bijective XCD swizzle)

typedef __bf16 bf16x8 __attribute__((ext_vector_type(8)));
typedef float f32x4 __attribute__((ext_vector_type(4)));

__device__ __forceinline__ unsigned short f2bf(float f) {
  union { float f; unsigned int u; } c; c.f = f;
  unsigned int u = c.u;
  u += 0x7fffu + ((u >> 16) & 1u);   // round-to-nearest-even
  return (unsigned short)(u >> 16);
}

__device__ __forceinline__ void gl_lds16(const unsigned short* g, unsigned short* l) {
  __builtin_amdgcn_global_load_lds(
      (const __attribute__((address_space(1))) unsigned int*)g,
      (__attribute__((address_space(3))) unsigned int*)l, 16, 0, 0);
}

// XOR-swizzled 128x32 bf16 tile (64B rows, swizzle at 128B/2-row units):
// logical (row R, 16B chunk fq) lives at physical chunk p = q ^ ((R>>1)&7),
// q = (R&1)*4 + fq. Measured conflict-free (SQ_LDS_BANK_CONFLICT = 0).
__device__ __forceinline__ int swz_off(int R, int fq) {
  int q = ((R & 1) << 2) | fq;
  int p = q ^ ((R >> 1) & 7);
  return (R >> 1) * 64 + p * 8;
}

// ---------------- routing ---------------------------------------------------
__global__ void moe_count(const int* __restrict__ idx, int* __restrict__ cnt) {
  int a = blockIdx.x * 256 + threadIdx.x;
  if (a < NA) atomicAdd(&cnt[idx[a]], 1);
}

__global__ void moe_scan(const int* __restrict__ cnt, int* __restrict__ seg,
                         int* __restrict__ work_e, int* __restrict__ work_r,
                         int* __restrict__ ntiles) {
  if (blockIdx.x == 0 && threadIdx.x == 0) {
    int off = 0, nt = 0;
    for (int e = 0; e < NE; ++e) {
      seg[e] = off;
      int c = cnt[e];
      int tiles = (c + 127) >> 7;
      for (int tb = 0; tb < tiles; ++tb) {
        work_e[nt] = e;
        work_r[nt] = off + tb * 128;
        ++nt;
      }
      off += tiles << 7;
    }
    *ntiles = nt;
  }
}

__global__ void moe_fill(const int* __restrict__ idx, const float* __restrict__ wts,
                         const int* __restrict__ seg, int* __restrict__ cnt2,
                         int* __restrict__ row_token, float* __restrict__ row_weight,
                         int* __restrict__ slot_of) {
  int a = blockIdx.x * 256 + threadIdx.x;
  if (a < NA) {
    int e = idx[a];
    int pos = atomicAdd(&cnt2[e], 1);
    int slot = seg[e] + pos;
    row_token[slot] = a >> 1;       // token id (K=2)
    row_weight[slot] = wts[a];
    slot_of[a] = slot;
  }
}

// ---------------- mega1: gather routed rows  +  cast gate/up fp32->bf16 ----
__global__ void mega_gather_castgu(
    const float* __restrict__ hidden, const int* __restrict__ slot_of,
    unsigned short* __restrict__ Xg,
    const float* __restrict__ gate_w, const float* __restrict__ up_w,
    unsigned short* __restrict__ gate_bf, unsigned short* __restrict__ ub_out) {
  const int bx = blockIdx.x;
  if (bx < NA) {
    // gather one assignment row: fp32 hidden -> bf16 Xg[slot]
    const int slot = slot_of[bx];
    const int t = bx >> 1;
    const float4* src = (const float4*)(hidden + (size_t)t * HD);
    ushort4* dst = (ushort4*)(Xg + (size_t)slot * HD);
#pragma unroll
    for (int j = 0; j < 2; ++j) {
      int i = threadIdx.x + j * 256;
      float4 v = src[i];
      ushort4 o;
      o.x = f2bf(v.x); o.y = f2bf(v.y); o.z = f2bf(v.z); o.w = f2bf(v.w);
      dst[i] = o;
    }
  } else {
    // grid-stride cast of gate_w then up_w (NT loads: single-use fp32 stream,
    // keep LLC for the bf16 working set)
    const int cb = bx - NA;
    const int total = 2 * N4;
    for (int i = cb * 256 + threadIdx.x; i < total; i += NCGU * 256) {
      const float* s; unsigned short* t; int j = i;
      if (j < N4) { s = gate_w; t = gate_bf; }
      else { s = up_w; t = ub_out; j -= N4; }
      f32x4 v = __builtin_nontemporal_load((const f32x4*)s + j);
      ushort4 o;
      o.x = f2bf(v[0]); o.y = f2bf(v[1]); o.z = f2bf(v[2]); o.w = f2bf(v[3]);
      ((ushort4*)t)[j] = o;
    }
  }
}

// ---------------- mega2: gate+up GEMM (SwiGLU epilogue) + cast down_w ------
// GEMM: C[m,i] = sum_h Xg[m,h] * W[e,i,h]  (NT), tile 128x128.
// 3-stage LDS pipeline, BK=32, loads 2 K-steps ahead, counted vmcnt(12).
__global__ __launch_bounds__(256, 2) void moe_gateup(
    const unsigned short* __restrict__ Xg,
    const unsigned short* __restrict__ Wg,
    const unsigned short* __restrict__ Wu,
    unsigned short* __restrict__ inter,
    const int* __restrict__ work_e, const int* __restrict__ work_r,
    const int* __restrict__ ntiles,
    const float* __restrict__ down_w, unsigned short* __restrict__ down_bf) {
  const int bx = blockIdx.x;
  if (bx >= NGEMM_GU) {
    // cast blocks LAST in grid: GEMM blocks get CUs first, cast backfills
    const int cb = bx - NGEMM_GU;
    for (int i = cb * 256 + threadIdx.x; i < N4; i += NCASTD * 256) {
      f32x4 v = __builtin_nontemporal_load((const f32x4*)down_w + i);
      ushort4 o;
      o.x = f2bf(v[0]); o.y = f2bf(v[1]); o.z = f2bf(v[2]); o.w = f2bf(v[3]);
      ((ushort4*)down_bf)[i] = o;
    }
    return;
  }
  // XCD-chunked swizzle: consecutive tiles (sharing a B panel) on one XCD
  const int g = (bx & 7) * (NGEMM_GU / 8) + (bx >> 3);
  const int tile = g % NTILE_M;
  if (tile >= *ntiles) return;
  const int e = work_e[tile];
  const int row0 = work_r[tile];
  const int col0 = (g / NTILE_M) * 128;

  __shared__ unsigned short As[3][128 * 32];
  __shared__ unsigned short Bgs[3][128 * 32];
  __shared__ unsigned short Bus[3][128 * 32];

  const int tid = threadIdx.x;
  const int lane = tid & 63;
  const int wave = tid >> 6;       // 0..3
  const int wm = wave >> 1, wn = wave & 1;
  // staging lane -> swizzled global source within a 16-row block
  const int p_l = lane & 7;
  const int ub  = lane >> 3;
  const int q_l = p_l ^ ub;
  const int srow = (ub << 1) | (q_l >> 2);
  const int scol = (q_l & 3) << 3;
  const int fm = lane & 15, fq = lane >> 4;

  const size_t a_base = (size_t)row0 * HD;
  const size_t b_base = ((size_t)e * ID + col0) * HD;

  f32x4 zero = {0.f, 0.f, 0.f, 0.f};
  f32x4 accg[4][4], accu[4][4];
#pragma unroll
  for (int mi = 0; mi < 4; ++mi)
#pragma unroll
    for (int ni = 0; ni < 4; ++ni) { accg[mi][ni] = zero; accu[mi][ni] = zero; }

  int offA[4], offB[4];
#pragma unroll
  for (int i = 0; i < 4; ++i) {
    offA[i] = swz_off(wm * 64 + i * 16 + fm, fq);
    offB[i] = swz_off(wn * 64 + i * 16 + fm, fq);
  }

  auto stage = [&](int k0, int st) {
#pragma unroll
    for (int h = 0; h < 2; ++h) {
      const int m0 = (wave << 5) + (h << 4);
      const size_t go = (size_t)(m0 + srow) * HD + k0 + scol;
      gl_lds16(Xg + a_base + go, &As[st][m0 * 32]);
      gl_lds16(Wg + b_base + go, &Bgs[st][m0 * 32]);
      gl_lds16(Wu + b_base + go, &Bus[st][m0 * 32]);
    }
  };

  auto compute = [&](int st) {
    bf16x8 a[4], bg[4], bu[4];
#pragma unroll
    for (int i = 0; i < 4; ++i) {
      a[i]  = *(const bf16x8*)&As[st][offA[i]];
      bg[i] = *(const bf16x8*)&Bgs[st][offB[i]];
      bu[i] = *(const bf16x8*)&Bus[st][offB[i]];
    }
    __builtin_amdgcn_s_setprio(1);
#pragma unroll
    for (int mi = 0; mi < 4; ++mi)
#pragma unroll
      for (int ni = 0; ni < 4; ++ni) {
        accg[mi][ni] = __builtin_amdgcn_mfma_f32_16x16x32_bf16(a[mi], bg[ni], accg[mi][ni], 0, 0, 0);
        accu[mi][ni] = __builtin_amdgcn_mfma_f32_16x16x32_bf16(a[mi], bu[ni], accu[mi][ni], 0, 0, 0);
      }
    __builtin_amdgcn_s_setprio(0);
  };

  // NK = HD/32 = 64 K-steps. Prologue: stages 0,1. Steady: barrier A (readers
  // of buf[(k-1)%3] done) -> stage(k+2) -> vmcnt(12) (my stage(k) landed) ->
  // barrier B (everyone's stage(k) landed) -> compute(k).
  stage(0, 0);
  stage(32, 1);
  int stc = 0, stp = 2, k0p = 64;
#pragma unroll 1
  for (int k = 0; k < 62; ++k) {
    __builtin_amdgcn_s_barrier();
    stage(k0p, stp);
    asm volatile("s_waitcnt vmcnt(12)" ::: "memory");
    __builtin_amdgcn_s_barrier();
    __builtin_amdgcn_sched_barrier(0);
    compute(stc);
    __builtin_amdgcn_sched_barrier(0);
    k0p += 32;
    stc = (stc == 2) ? 0 : stc + 1;
    stp = (stp == 2) ? 0 : stp + 1;
  }
  __builtin_amdgcn_s_barrier();
  asm volatile("s_waitcnt vmcnt(6)" ::: "memory");
  __builtin_amdgcn_s_barrier();
  __builtin_amdgcn_sched_barrier(0);
  compute(2);                       // k=62 -> 62%3
  __builtin_amdgcn_s_barrier();
  asm volatile("s_waitcnt vmcnt(0)" ::: "memory");
  __builtin_amdgcn_s_barrier();
  __builtin_amdgcn_sched_barrier(0);
  compute(0);                       // k=63 -> 63%3

  // SwiGLU epilogue -> inter (bf16). Padded rows computed too (harmless).
#pragma unroll
  for (int mi = 0; mi < 4; ++mi)
#pragma unroll
    for (int ni = 0; ni < 4; ++ni)
#pragma unroll
      for (int r = 0; r < 4; ++r) {
        float gg = accg[mi][ni][r];
        float u = accu[mi][ni][r];
        float v = (gg / (1.0f + __expf(-gg))) * u;
        int row = row0 + wm * 64 + mi * 16 + fq * 4 + r;
        int col = col0 + wn * 64 + ni * 16 + fm;
        inter[(size_t)row * ID + col] = f2bf(v);
      }
}

// ---------------- phase B: down GEMM, weighted atomic scatter ---------------
// C[m,h] = sum_i inter[m,i] * Wd[e,h,i]; out[token[m],h] += w[m]*C[m,h]
// Same 3-stage counted-vmcnt pipeline (2 matrices -> vmcnt(8)).
__global__ __launch_bounds__(256, 2) void moe_down(
    const unsigned short* __restrict__ inter,
    const unsigned short* __restrict__ Wd,
    float* __restrict__ out,
    const int* __restrict__ work_e, const int* __restrict__ work_r,
    const int* __restrict__ ntiles,
    const int* __restrict__ row_token, const float* __restrict__ row_weight) {
  const int tile = blockIdx.x;
  if (tile >= *ntiles) return;
  const int e = work_e[tile];
  const int row0 = work_r[tile];
  const int col0 = blockIdx.y * 128;   // h dim

  __shared__ unsigned short As[3][128 * 32];
  __shared__ unsigned short Bs[3][128 * 32];
  __shared__ int tok_s[128];
  __shared__ float w_s[128];

  const int tid = threadIdx.x;
  if (tid < 128) {
    tok_s[tid] = row_token[row0 + tid];
    w_s[tid] = row_weight[row0 + tid];
  }

  const int lane = tid & 63;
  const int wave = tid >> 6;
  const int wm = wave >> 1, wn = wave & 1;
  const int p_l = lane & 7;
  const int ub  = lane >> 3;
  const int q_l = p_l ^ ub;
  const int srow = (ub << 1) | (q_l >> 2);
  const int scol = (q_l & 3) << 3;
  const int fm = lane & 15, fq = lane >> 4;

  const size_t a_base = (size_t)row0 * ID;
  const size_t b_base = ((size_t)e * HD + col0) * ID;

  f32x4 zero = {0.f, 0.f, 0.f, 0.f};
  f32x4 acc[4][4];
#pragma unroll
  for (int mi = 0; mi < 4; ++mi)
#pragma unroll
    for (int ni = 0; ni < 4; ++ni) acc[mi][ni] = zero;

  int offA[4], offB[4];
#pragma unroll
  for (int i = 0; i < 4; ++i) {
    offA[i] = swz_off(wm * 64 + i * 16 + fm, fq);
    offB[i] = swz_off(wn * 64 + i * 16 + fm, fq);
  }

  auto stage = [&](int k0, int st) {
#pragma unroll
    for (int h = 0; h < 2; ++h) {
      const int m0 = (wave << 5) + (h << 4);
      const size_t go = (size_t)(m0 + srow) * ID + k0 + scol;
      gl_lds16(inter + a_base + go, &As[st][m0 * 32]);
      gl_lds16(Wd + b_base + go, &Bs[st][m0 * 32]);
    }
  };

  auto compute = [&](int st) {
    bf16x8 a[4], b[4];
#pragma unroll
    for (int i = 0; i < 4; ++i) {
      a[i] = *(const bf16x8*)&As[st][offA[i]];
      b[i] = *(const bf16x8*)&Bs[st][offB[i]];
    }
    __builtin_amdgcn_s_setprio(1);
#pragma unroll
    for (int mi = 0; mi < 4; ++mi)
#pragma unroll
      for (int ni = 0; ni < 4; ++ni)
        acc[mi][ni] = __builtin_amdgcn_mfma_f32_16x16x32_bf16(a[mi], b[ni], acc[mi][ni], 0, 0, 0);
    __builtin_amdgcn_s_setprio(0);
  };

  // NK = ID/32 = 44
  stage(0, 0);
  stage(32, 1);
  int stc = 0, stp = 2, k0p = 64;
#pragma unroll 1
  for (int k = 0; k < 42; ++k) {
    __builtin_amdgcn_s_barrier();
    stage(k0p, stp);
    asm volatile("s_waitcnt vmcnt(8)" ::: "memory");
    __builtin_amdgcn_s_barrier();
    __builtin_amdgcn_sched_barrier(0);
    compute(stc);
    __builtin_amdgcn_sched_barrier(0);
    k0p += 32;
    stc = (stc == 2) ? 0 : stc + 1;
    stp = (stp == 2) ? 0 : stp + 1;
  }
  __builtin_amdgcn_s_barrier();
  asm volatile("s_waitcnt vmcnt(4)" ::: "memory");
  __builtin_amdgcn_s_barrier();
  __builtin_amdgcn_sched_barrier(0);
  compute(0);                       // k=42 -> 42%3
  __builtin_amdgcn_s_barrier();
  asm volatile("s_waitcnt vmcnt(0)" ::: "memory");
  __builtin_amdgcn_s_barrier();
  __builtin_amdgcn_sched_barrier(0);
  compute(1);                       // k=43 -> 43%3

#pragma unroll
  for (int mi = 0; mi < 4; ++mi)
#pragma unroll
    for (int ni = 0; ni < 4; ++ni)
#pragma unroll
      for (int r = 0; r < 4; ++r) {
        int rl = wm * 64 + mi * 16 + fq * 4 + r;
        int tok = tok_s[rl];
        if (tok >= 0) {
          int col = col0 + wn * 64 + ni * 16 + fm;
          atomicAdd(&out[(size_t)tok * HD + col], w_s[rl] * acc[mi][ni][r]);
        }
      }
}

// ---------------- host ------------------------------------------------------
extern "C" void kernel_launch(void* const* d_in, const int* in_sizes, int n_in,
                              void* d_out, int out_size, void* d_ws, size_t ws_size,
                              hipStream_t stream) {
  const float* hidden = (const float*)d_in[0];
  const int* topk_idx = (const int*)d_in[1];
  const float* topk_w = (const float*)d_in[2];
  const float* gate_w = (const float*)d_in[3];
  const float* up_w = (const float*)d_in[4];
  const float* down_w = (const float*)d_in[5];
  float* out = (float*)d_out;

  char* ws = (char*)d_ws;
  size_t o_gate = 0;
  size_t o_up   = o_gate + EIH * 2;
  size_t o_down = o_up + EIH * 2;
  size_t o_xg   = o_down + EIH * 2;
  size_t o_int  = o_xg + (size_t)MAXR * HD * 2;
  size_t o_tok  = o_int + (size_t)MAXR * ID * 2;
  size_t o_wgt  = o_tok + (size_t)MAXR * 4;
  size_t o_slot = o_wgt + (size_t)MAXR * 4;
  size_t o_small = o_slot + (size_t)NA * 4;

  unsigned short* gate_bf = (unsigned short*)(ws + o_gate);
  unsigned short* up_bf   = (unsigned short*)(ws + o_up);
  unsigned short* down_bf = (unsigned short*)(ws + o_down);
  unsigned short* Xg      = (unsigned short*)(ws + o_xg);
  unsigned short* inter   = (unsigned short*)(ws + o_int);
  int* row_token = (int*)(ws + o_tok);
  float* row_weight = (float*)(ws + o_wgt);
  int* slot_of = (int*)(ws + o_slot);
  int* cnt    = (int*)(ws + o_small);
  int* cnt2   = cnt + 8;
  int* seg    = cnt + 16;
  int* ntiles = cnt + 24;
  int* work_e = cnt + 32;
  int* work_r = cnt + 32 + MAXT;

  // zero output + routing state; mark all row slots invalid (-1)
  hipMemsetAsync(out, 0, (size_t)T_TOK * HD * 4, stream);
  hipMemsetAsync(cnt, 0, (32 + 2 * MAXT) * 4, stream);
  hipMemsetAsync(row_token, 0xFF, (size_t)MAXR * 4, stream);

  moe_count<<<NA / 256, 256, 0, stream>>>(topk_idx, cnt);
  moe_scan<<<1, 64, 0, stream>>>(cnt, seg, work_e, work_r, ntiles);
  moe_fill<<<NA / 256, 256, 0, stream>>>(topk_idx, topk_w, seg, cnt2,
                                         row_token, row_weight, slot_of);

  // mega1: gather (8192 blocks) + cast gate/up (2048 blocks)
  mega_gather_castgu<<<NA + NCGU, 256, 0, stream>>>(hidden, slot_of, Xg,
                                                    gate_w, up_w, gate_bf, up_bf);

  // mega2: gate/up GEMM first (792 blocks), down-cast backfills (1024 blocks)
  moe_gateup<<<NGEMM_GU + NCASTD, 256, 0, stream>>>(
      Xg, gate_bf, up_bf, inter, work_e, work_r, ntiles, down_w, down_bf);

  dim3 gridB(NTILE_M, HD / 128);   // 72 x 16
  moe_down<<<gridB, 256, 0, stream>>>(inter, down_bf, out, work_e, work_r, ntiles,
                                      row_token, row_weight);
}